// Round 1
// baseline (281.987 us; speedup 1.0000x reference)
//
#include <hip/hip_runtime.h>
#include <math.h>

#define B_ 2
#define T_ 2048
#define D_ 512
#define H_ 16
#define DH 32
#define L_ 64
#define C_ (T_/L_)   // 32 chunks
#define BH (B_*H_)   // 32

__device__ __forceinline__ float phi_f(float x) {
    // elu(x)+1 : x>0 -> x+1 ; else exp(x)
    return x > 0.0f ? x + 1.0f : expf(x);
}

// C[m][n] = sum_k A[m][k] * W[n][k]   (A: MxK row-major, W: NxK row-major)
template<int BM, int BN, int BK>
__global__ __launch_bounds__(256) void gemm_nt(const float* __restrict__ A,
                                               const float* __restrict__ W,
                                               float* __restrict__ C,
                                               int M, int N, int K)
{
    __shared__ float As[BK][BM + 1];
    __shared__ float Ws[BK][BN + 1];
    const int tid = threadIdx.x;
    const int bm = blockIdx.x * BM;
    const int bn = blockIdx.y * BN;
    const int tx = tid % 16;   // n direction
    const int ty = tid / 16;   // m direction
    float acc[4][4] = {};
    for (int k0 = 0; k0 < K; k0 += BK) {
        for (int idx = tid; idx < BM * BK; idx += 256) {
            int r = idx / BK, c = idx % BK;
            As[c][r] = A[(size_t)(bm + r) * K + k0 + c];
        }
        for (int idx = tid; idx < BN * BK; idx += 256) {
            int r = idx / BK, c = idx % BK;
            Ws[c][r] = W[(size_t)(bn + r) * K + k0 + c];
        }
        __syncthreads();
        #pragma unroll
        for (int kk = 0; kk < BK; ++kk) {
            float a[4], w[4];
            #pragma unroll
            for (int i = 0; i < 4; ++i) a[i] = As[kk][ty * 4 + i];
            #pragma unroll
            for (int j = 0; j < 4; ++j) w[j] = Ws[kk][tx * 4 + j];
            #pragma unroll
            for (int i = 0; i < 4; ++i)
                #pragma unroll
                for (int j = 0; j < 4; ++j)
                    acc[i][j] += a[i] * w[j];
        }
        __syncthreads();
    }
    for (int i = 0; i < 4; ++i)
        for (int j = 0; j < 4; ++j)
            C[(size_t)(bm + ty * 4 + i) * N + bn + tx * 4 + j] = acc[i][j];
}

// Per-chunk local sums: S_c[d][e] = sum_t phi(k)[d] * v[e] ; Ksum_c[d] = sum_t phi(k)[d]
__global__ __launch_bounds__(256) void chunk_sum(const float* __restrict__ qkv,
                                                 float* __restrict__ cS,
                                                 float* __restrict__ cK)
{
    __shared__ float kc[L_][DH];
    __shared__ float vc[L_][DH];
    const int bid = blockIdx.x;
    const int c = bid % C_;
    const int h = (bid / C_) % H_;
    const int b = bid / (C_ * H_);
    const int t0 = c * L_;
    const int tid = threadIdx.x;
    for (int idx = tid; idx < L_ * DH; idx += 256) {
        int t = idx / DH, d = idx % DH;
        const float* base = qkv + ((size_t)(b * T_ + t0 + t)) * (3 * D_) + h * DH + d;
        kc[t][d] = phi_f(base[D_]);
        vc[t][d] = base[2 * D_];
    }
    __syncthreads();
    // 1024 (d,e) pairs, 4 consecutive e per thread
    const int d = tid / 8;            // (tid*4)/32
    const int e0 = (tid * 4) % DH;
    float acc[4] = {0.f, 0.f, 0.f, 0.f};
    for (int t = 0; t < L_; ++t) {
        float kd = kc[t][d];
        #pragma unroll
        for (int i = 0; i < 4; ++i) acc[i] += kd * vc[t][e0 + i];
    }
    float* Sout = cS + (size_t)bid * (DH * DH);
    #pragma unroll
    for (int i = 0; i < 4; ++i) Sout[d * DH + e0 + i] = acc[i];
    if (tid < DH) {
        float s = 0.f;
        for (int t = 0; t < L_; ++t) s += kc[t][tid];
        cK[bid * DH + tid] = s;
    }
}

// Convert per-chunk inclusive local sums to EXCLUSIVE prefix states, elementwise.
__global__ void chunk_scan(float* __restrict__ cS, float* __restrict__ cK)
{
    const int idx = blockIdx.x * blockDim.x + threadIdx.x;
    const int NS = BH * DH * DH;   // 32768
    if (idx < NS) {
        int bh = idx / (DH * DH);
        int j = idx % (DH * DH);
        float acc = 0.f;
        for (int c = 0; c < C_; ++c) {
            float* p = cS + ((size_t)(bh * C_ + c)) * (DH * DH) + j;
            float t = *p; *p = acc; acc += t;
        }
    } else {
        int k = idx - NS;
        if (k < BH * DH) {
            int bh = k / DH, j = k % DH;
            float acc = 0.f;
            for (int c = 0; c < C_; ++c) {
                float* p = cK + (size_t)(bh * C_ + c) * DH + j;
                float t = *p; *p = acc; acc += t;
            }
        }
    }
}

// Per-chunk output: num = q@KV0 + (causal QK^T)@V ; den = q.ksum0 + row-sum of masked scores
__global__ __launch_bounds__(256) void chunk_out(const float* __restrict__ qkv,
                                                 const float* __restrict__ cS,
                                                 const float* __restrict__ cK,
                                                 float* __restrict__ attn)
{
    __shared__ float qc[L_][DH + 1];
    __shared__ float kc[L_][DH + 1];
    __shared__ float vc[L_][DH + 1];
    __shared__ float KV0[DH][DH + 1];
    __shared__ float ks0[DH];
    __shared__ float Am[L_][L_ + 1];
    const int bid = blockIdx.x;
    const int c = bid % C_;
    const int h = (bid / C_) % H_;
    const int b = bid / (C_ * H_);
    const int t0 = c * L_;
    const int tid = threadIdx.x;
    for (int idx = tid; idx < L_ * DH; idx += 256) {
        int t = idx / DH, d = idx % DH;
        const float* base = qkv + ((size_t)(b * T_ + t0 + t)) * (3 * D_) + h * DH + d;
        qc[t][d] = phi_f(base[0]);
        kc[t][d] = phi_f(base[D_]);
        vc[t][d] = base[2 * D_];
    }
    for (int idx = tid; idx < DH * DH; idx += 256) {
        int d = idx / DH, e = idx % DH;
        KV0[d][e] = cS[(size_t)bid * (DH * DH) + idx];
    }
    if (tid < DH) ks0[tid] = cK[bid * DH + tid];
    __syncthreads();
    // masked causal scores A[i][j] = (j<=i) ? q_i . k_j : 0
    for (int idx = tid; idx < L_ * L_; idx += 256) {
        int i = idx / L_, j = idx % L_;
        float s = 0.f;
        if (j <= i) {
            #pragma unroll
            for (int d = 0; d < DH; ++d) s += qc[i][d] * kc[j][d];
        }
        Am[i][j] = s;
    }
    __syncthreads();
    // outputs: thread covers e = tid%32, rows i = tid/32 + 8*r
    const int e = tid % DH;
    const int i0 = tid / DH;
    for (int r = 0; r < L_ / 8; ++r) {
        int i = i0 + 8 * r;
        float num = 0.f, den = 0.f;
        #pragma unroll
        for (int d = 0; d < DH; ++d) {
            float qd = qc[i][d];
            num += qd * KV0[d][e];
            den += qd * ks0[d];
        }
        #pragma unroll 8
        for (int j = 0; j < L_; ++j) {
            float a = Am[i][j];
            num += a * vc[j][e];
            den += a;
        }
        den = fmaxf(den, 1e-6f);
        attn[((size_t)(b * T_ + t0 + i)) * D_ + h * DH + e] = num / den;
    }
}

extern "C" void kernel_launch(void* const* d_in, const int* in_sizes, int n_in,
                              void* d_out, int out_size, void* d_ws, size_t ws_size,
                              hipStream_t stream) {
    const float* x     = (const float*)d_in[0];
    const float* w_qkv = (const float*)d_in[1];
    const float* w_out = (const float*)d_in[2];
    float* out = (float*)d_out;
    float* ws = (float*)d_ws;

    float* qkv  = ws;                              // B*T*3D   = 6,291,456 f
    float* cS   = qkv + (size_t)B_ * T_ * 3 * D_;  // BH*C*32*32 = 1,048,576 f
    float* cK   = cS + (size_t)BH * C_ * DH * DH;  // BH*C*32  = 32,768 f
    float* attn = cK + (size_t)BH * C_ * DH;       // B*T*D    = 2,097,152 f

    // 1) QKV projection: (4096 x 512) @ (512 x 1536)^T
    dim3 g1(4096 / 64, 1536 / 64);
    gemm_nt<64, 64, 16><<<g1, 256, 0, stream>>>(x, w_qkv, qkv, 4096, 1536, 512);

    // 2) per-chunk local sums
    chunk_sum<<<BH * C_, 256, 0, stream>>>(qkv, cS, cK);

    // 3) exclusive prefix over chunks (elementwise, no sync)
    chunk_scan<<<132, 256, 0, stream>>>(cS, cK);

    // 4) per-chunk outputs
    chunk_out<<<BH * C_, 256, 0, stream>>>(qkv, cS, cK, attn);

    // 5) output projection: (4096 x 512) @ (512 x 512)^T
    dim3 g2(4096 / 64, 512 / 64);
    gemm_nt<64, 64, 16><<<g2, 256, 0, stream>>>(attn, w_out, out, 4096, 512, 512);
}

// Round 2
// 103.712 us; speedup vs baseline: 2.7189x; 2.7189x over previous
//
#include <hip/hip_runtime.h>
#include <math.h>

#define B_ 2
#define T_ 2048
#define D_ 512
#define H_ 16
#define DH 32
#define L_ 64
#define C_ (T_/L_)   // 32 chunks
#define BH (B_*H_)   // 32

typedef __attribute__((ext_vector_type(8))) short bf16x8;
typedef __attribute__((ext_vector_type(4))) float f32x4;
typedef __attribute__((ext_vector_type(4))) unsigned short u16x4;

__device__ __forceinline__ float phi_f(float x) {
    return x > 0.0f ? x + 1.0f : expf(x);
}

__device__ __forceinline__ float bf2f(unsigned short u) {
    union { float f; unsigned int i; } v; v.i = ((unsigned int)u) << 16; return v.f;
}

__device__ __forceinline__ unsigned short f2bf(float f) {
    union { float f; unsigned int u; } v; v.f = f;
    unsigned int u = v.u;
    unsigned int r = u + 0x7FFFu + ((u >> 16) & 1u);
    return (unsigned short)(r >> 16);
}

__global__ __launch_bounds__(256) void f32_to_bf16(const float* __restrict__ in,
                                                   unsigned short* __restrict__ out, int n4) {
    int i = blockIdx.x * 256 + threadIdx.x;
    if (i < n4) {
        float4 v = ((const float4*)in)[i];
        u16x4 o;
        o.x = f2bf(v.x); o.y = f2bf(v.y); o.z = f2bf(v.z); o.w = f2bf(v.w);
        ((u16x4*)out)[i] = o;
    }
}

// C[m][n] = sum_k A[m][k]*W[n][k]; A:MxK bf16 row-major, W:NxK bf16 row-major.
// 128x128 tile, 4 waves (2x2), each wave 64x64 via 4x4 frags of 16x16x32 MFMA.
template<bool OUT_BF16>
__global__ __launch_bounds__(256) void gemm_bf16_nt(const unsigned short* __restrict__ A,
                                                    const unsigned short* __restrict__ W,
                                                    void* __restrict__ Cout,
                                                    int M, int N, int K)
{
    __shared__ unsigned short As[128][40];   // +8 pad: row stride 80B (16B aligned, 2-way banks = free)
    __shared__ unsigned short Bs[128][40];
    const int tid = threadIdx.x;
    const int lane = tid & 63;
    const int wave = tid >> 6;
    const int wr = wave >> 1;
    const int wc = wave & 1;
    const size_t bm = (size_t)blockIdx.x * 128;
    const size_t bn = (size_t)blockIdx.y * 128;

    f32x4 acc[4][4];
    #pragma unroll
    for (int m = 0; m < 4; ++m)
        #pragma unroll
        for (int n = 0; n < 4; ++n)
            acc[m][n] = (f32x4){0.f, 0.f, 0.f, 0.f};

    const int rr = lane & 15;
    const int kb = (lane >> 4) * 8;

    for (int k0 = 0; k0 < K; k0 += 32) {
        #pragma unroll
        for (int i = 0; i < 2; ++i) {
            int chunk = tid + 256 * i;
            int row = chunk >> 2;
            int co = (chunk & 3) * 8;
            *(uint4*)&As[row][co] = *(const uint4*)&A[(bm + row) * K + k0 + co];
            *(uint4*)&Bs[row][co] = *(const uint4*)&W[(bn + row) * K + k0 + co];
        }
        __syncthreads();
        bf16x8 af[4], bfr[4];
        #pragma unroll
        for (int m = 0; m < 4; ++m) af[m] = *(const bf16x8*)&As[wr * 64 + m * 16 + rr][kb];
        #pragma unroll
        for (int n = 0; n < 4; ++n) bfr[n] = *(const bf16x8*)&Bs[wc * 64 + n * 16 + rr][kb];
        #pragma unroll
        for (int m = 0; m < 4; ++m)
            #pragma unroll
            for (int n = 0; n < 4; ++n)
                acc[m][n] = __builtin_amdgcn_mfma_f32_16x16x32_bf16(af[m], bfr[n], acc[m][n], 0, 0, 0);
        __syncthreads();
    }

    const int cr = (lane >> 4) * 4;
    const int cc = lane & 15;
    #pragma unroll
    for (int m = 0; m < 4; ++m)
        #pragma unroll
        for (int n = 0; n < 4; ++n)
            #pragma unroll
            for (int j = 0; j < 4; ++j) {
                size_t row = bm + wr * 64 + m * 16 + cr + j;
                size_t col = bn + wc * 64 + n * 16 + cc;
                float v = acc[m][n][j];
                if (OUT_BF16) ((unsigned short*)Cout)[row * N + col] = f2bf(v);
                else          ((float*)Cout)[row * N + col] = v;
            }
}

// Per-chunk local sums from bf16 qkv
__global__ __launch_bounds__(256) void chunk_sum(const unsigned short* __restrict__ qkv,
                                                 float* __restrict__ cS,
                                                 float* __restrict__ cK)
{
    __shared__ float kc[L_][DH];
    __shared__ float vc[L_][DH];
    const int bid = blockIdx.x;
    const int c = bid % C_;
    const int h = (bid / C_) % H_;
    const int b = bid / (C_ * H_);
    const int t0 = c * L_;
    const int tid = threadIdx.x;
    for (int idx = tid; idx < L_ * DH; idx += 256) {
        int t = idx / DH, d = idx % DH;
        const unsigned short* base = qkv + ((size_t)(b * T_ + t0 + t)) * (3 * D_) + h * DH + d;
        kc[t][d] = phi_f(bf2f(base[D_]));
        vc[t][d] = bf2f(base[2 * D_]);
    }
    __syncthreads();
    const int d = tid / 8;
    const int e0 = (tid * 4) % DH;
    float acc[4] = {0.f, 0.f, 0.f, 0.f};
    for (int t = 0; t < L_; ++t) {
        float kd = kc[t][d];
        #pragma unroll
        for (int i = 0; i < 4; ++i) acc[i] += kd * vc[t][e0 + i];
    }
    float* Sout = cS + (size_t)bid * (DH * DH);
    #pragma unroll
    for (int i = 0; i < 4; ++i) Sout[d * DH + e0 + i] = acc[i];
    if (tid < DH) {
        float s = 0.f;
        for (int t = 0; t < L_; ++t) s += kc[t][tid];
        cK[bid * DH + tid] = s;
    }
}

__global__ void chunk_scan(float* __restrict__ cS, float* __restrict__ cK)
{
    const int idx = blockIdx.x * blockDim.x + threadIdx.x;
    const int NS = BH * DH * DH;
    if (idx < NS) {
        int bh = idx / (DH * DH);
        int j = idx % (DH * DH);
        float acc = 0.f;
        for (int c = 0; c < C_; ++c) {
            float* p = cS + ((size_t)(bh * C_ + c)) * (DH * DH) + j;
            float t = *p; *p = acc; acc += t;
        }
    } else {
        int k = idx - NS;
        if (k < BH * DH) {
            int bh = k / DH, j = k % DH;
            float acc = 0.f;
            for (int c = 0; c < C_; ++c) {
                float* p = cK + (size_t)(bh * C_ + c) * DH + j;
                float t = *p; *p = acc; acc += t;
            }
        }
    }
}

__global__ __launch_bounds__(256) void chunk_out(const unsigned short* __restrict__ qkv,
                                                 const float* __restrict__ cS,
                                                 const float* __restrict__ cK,
                                                 unsigned short* __restrict__ attn)
{
    __shared__ float qc[L_][DH + 1];
    __shared__ float kc[L_][DH + 1];
    __shared__ float vc[L_][DH + 1];
    __shared__ float KV0[DH][DH + 1];
    __shared__ float ks0[DH];
    __shared__ float Am[L_][L_ + 1];
    const int bid = blockIdx.x;
    const int c = bid % C_;
    const int h = (bid / C_) % H_;
    const int b = bid / (C_ * H_);
    const int t0 = c * L_;
    const int tid = threadIdx.x;
    for (int idx = tid; idx < L_ * DH; idx += 256) {
        int t = idx / DH, d = idx % DH;
        const unsigned short* base = qkv + ((size_t)(b * T_ + t0 + t)) * (3 * D_) + h * DH + d;
        qc[t][d] = phi_f(bf2f(base[0]));
        kc[t][d] = phi_f(bf2f(base[D_]));
        vc[t][d] = bf2f(base[2 * D_]);
    }
    for (int idx = tid; idx < DH * DH; idx += 256) {
        KV0[idx / DH][idx % DH] = cS[(size_t)bid * (DH * DH) + idx];
    }
    if (tid < DH) ks0[tid] = cK[bid * DH + tid];
    __syncthreads();
    for (int idx = tid; idx < L_ * L_; idx += 256) {
        int i = idx / L_, j = idx % L_;
        float s = 0.f;
        if (j <= i) {
            #pragma unroll
            for (int d = 0; d < DH; ++d) s += qc[i][d] * kc[j][d];
        }
        Am[i][j] = s;
    }
    __syncthreads();
    const int e = tid % DH;
    const int i0 = tid / DH;
    for (int r = 0; r < L_ / 8; ++r) {
        int i = i0 + 8 * r;
        float num = 0.f, den = 0.f;
        #pragma unroll
        for (int d = 0; d < DH; ++d) {
            float qd = qc[i][d];
            num += qd * KV0[d][e];
            den += qd * ks0[d];
        }
        #pragma unroll 8
        for (int j = 0; j < L_; ++j) {
            float a = Am[i][j];
            num += a * vc[j][e];
            den += a;
        }
        den = fmaxf(den, 1e-6f);
        attn[((size_t)(b * T_ + t0 + i)) * D_ + h * DH + e] = f2bf(num / den);
    }
}

extern "C" void kernel_launch(void* const* d_in, const int* in_sizes, int n_in,
                              void* d_out, int out_size, void* d_ws, size_t ws_size,
                              hipStream_t stream) {
    const float* x     = (const float*)d_in[0];
    const float* w_qkv = (const float*)d_in[1];
    const float* w_out = (const float*)d_in[2];
    float* out = (float*)d_out;

    char* ws = (char*)d_ws;
    unsigned short* qkvb = (unsigned short*)ws;                 // 6,291,456 bf16 = 12,582,912 B
    unsigned short* attnb = (unsigned short*)(ws + 12582912);   // 2,097,152 bf16 =  4,194,304 B
    unsigned short* xb    = (unsigned short*)(ws + 16777216);   // 2,097,152 bf16 =  4,194,304 B
    unsigned short* wqb   = (unsigned short*)(ws + 20971520);   //   786,432 bf16 =  1,572,864 B
    unsigned short* wob   = (unsigned short*)(ws + 22544384);   //   262,144 bf16 =    524,288 B
    float* cS             = (float*)(ws + 23068672);            // 1,048,576 f32  =  4,194,304 B
    float* cK             = (float*)(ws + 27262976);            //    32,768 f32  =    131,072 B
    // total 27,394,048 B

    // 0) fp32 -> bf16 conversions
    f32_to_bf16<<<(2097152 / 4 + 255) / 256, 256, 0, stream>>>(x, xb, 2097152 / 4);
    f32_to_bf16<<<(786432 / 4 + 255) / 256, 256, 0, stream>>>(w_qkv, wqb, 786432 / 4);
    f32_to_bf16<<<(262144 / 4 + 255) / 256, 256, 0, stream>>>(w_out, wob, 262144 / 4);

    // 1) QKV projection (bf16 MFMA): (4096x512)@(512x1536)^T -> bf16 qkv
    dim3 g1(4096 / 128, 1536 / 128);
    gemm_bf16_nt<true><<<g1, 256, 0, stream>>>(xb, wqb, qkvb, 4096, 1536, 512);

    // 2) per-chunk local sums
    chunk_sum<<<BH * C_, 256, 0, stream>>>(qkvb, cS, cK);

    // 3) exclusive prefix over chunks
    chunk_scan<<<132, 256, 0, stream>>>(cS, cK);

    // 4) per-chunk outputs -> bf16 attn
    chunk_out<<<BH * C_, 256, 0, stream>>>(qkvb, cS, cK, attnb);

    // 5) output projection (bf16 MFMA): (4096x512)@(512x512)^T -> fp32 out
    dim3 g2(4096 / 128, 512 / 128);
    gemm_bf16_nt<false><<<g2, 256, 0, stream>>>(attnb, wob, out, 4096, 512, 512);
}

// Round 3
// 61.091 us; speedup vs baseline: 4.6158x; 1.6977x over previous
//
#include <hip/hip_runtime.h>
#include <math.h>

#define B_ 2
#define T_ 2048
#define D_ 512
#define H_ 16
#define DH 32
#define L_ 64
#define C_ 32
#define BH 32
#define NC 1024   // total chunks
#define VTP 72    // LDS row stride (ushorts): 144B, 16B-aligned, 2-way banks

typedef __attribute__((ext_vector_type(8))) short bf16x8;
typedef __attribute__((ext_vector_type(4))) float f32x4;
typedef __attribute__((ext_vector_type(4))) unsigned short u16x4;

__device__ __forceinline__ float bf2f(unsigned short u) {
    union { float f; unsigned int i; } v; v.i = ((unsigned int)u) << 16; return v.f;
}
__device__ __forceinline__ unsigned short f2bf(float f) {
    union { float f; unsigned int u; } v; v.f = f;
    unsigned int u = v.u;
    unsigned int r = u + 0x7FFFu + ((u >> 16) & 1u);
    return (unsigned short)(r >> 16);
}
__device__ __forceinline__ bf16x8 phi_frag(bf16x8 in) {
    bf16x8 r;
    #pragma unroll
    for (int i = 0; i < 8; ++i) {
        float f = bf2f((unsigned short)in[i]);
        f = f > 0.f ? f + 1.f : __expf(f);
        r[i] = (short)f2bf(f);
    }
    return r;
}

__global__ __launch_bounds__(256) void f32_to_bf16(const float* __restrict__ in,
                                                   unsigned short* __restrict__ out, int n4) {
    int i = blockIdx.x * 256 + threadIdx.x;
    if (i < n4) {
        float4 v = ((const float4*)in)[i];
        u16x4 o;
        o.x = f2bf(v.x); o.y = f2bf(v.y); o.z = f2bf(v.z); o.w = f2bf(v.w);
        ((u16x4*)out)[i] = o;
    }
}

// C[m][n] = sum_k A[m][k]*W[n][k]; 128x128 tile, 4 waves, 16x16x32 bf16 MFMA.
template<bool OUT_BF16>
__global__ __launch_bounds__(256) void gemm_bf16_nt(const unsigned short* __restrict__ A,
                                                    const unsigned short* __restrict__ W,
                                                    void* __restrict__ Cout,
                                                    int M, int N, int K)
{
    __shared__ unsigned short As[128][40];
    __shared__ unsigned short Bs[128][40];
    const int tid = threadIdx.x;
    const int lane = tid & 63;
    const int wave = tid >> 6;
    const int wr = wave >> 1;
    const int wc = wave & 1;
    const size_t bm = (size_t)blockIdx.x * 128;
    const size_t bn = (size_t)blockIdx.y * 128;

    f32x4 acc[4][4];
    #pragma unroll
    for (int m = 0; m < 4; ++m)
        #pragma unroll
        for (int n = 0; n < 4; ++n)
            acc[m][n] = (f32x4){0.f, 0.f, 0.f, 0.f};

    const int rr = lane & 15;
    const int kb = (lane >> 4) * 8;

    for (int k0 = 0; k0 < K; k0 += 32) {
        #pragma unroll
        for (int i = 0; i < 2; ++i) {
            int chunk = tid + 256 * i;
            int row = chunk >> 2;
            int co = (chunk & 3) * 8;
            *(uint4*)&As[row][co] = *(const uint4*)&A[(bm + row) * K + k0 + co];
            *(uint4*)&Bs[row][co] = *(const uint4*)&W[(bn + row) * K + k0 + co];
        }
        __syncthreads();
        bf16x8 af[4], bfr[4];
        #pragma unroll
        for (int m = 0; m < 4; ++m) af[m] = *(const bf16x8*)&As[wr * 64 + m * 16 + rr][kb];
        #pragma unroll
        for (int n = 0; n < 4; ++n) bfr[n] = *(const bf16x8*)&Bs[wc * 64 + n * 16 + rr][kb];
        #pragma unroll
        for (int m = 0; m < 4; ++m)
            #pragma unroll
            for (int n = 0; n < 4; ++n)
                acc[m][n] = __builtin_amdgcn_mfma_f32_16x16x32_bf16(af[m], bfr[n], acc[m][n], 0, 0, 0);
        __syncthreads();
    }

    const int cr = (lane >> 4) * 4;
    const int cc = lane & 15;
    #pragma unroll
    for (int m = 0; m < 4; ++m)
        #pragma unroll
        for (int n = 0; n < 4; ++n)
            #pragma unroll
            for (int j = 0; j < 4; ++j) {
                size_t row = bm + wr * 64 + m * 16 + cr + j;
                size_t col = bn + wc * 64 + n * 16 + cc;
                float v = acc[m][n][j];
                if (OUT_BF16) ((unsigned short*)Cout)[row * N + col] = f2bf(v);
                else          ((float*)Cout)[row * N + col] = v;
            }
}

// Per-chunk ST[e][d] = sum_t v_ext[t][e]*phi(k)[t][d], e=0..32 (row 32 = ksum).
// One wave per chunk; MFMA 16x16x32.
__global__ __launch_bounds__(256) void chunk_sum(const unsigned short* __restrict__ qkv,
                                                 float* __restrict__ cSf)
{
    __shared__ unsigned short Kt[4][DH][VTP];
    __shared__ unsigned short Vt[4][48][VTP];
    const int tid = threadIdx.x;
    const int lane = tid & 63;
    const int wave = tid >> 6;
    const int chunk = blockIdx.x * 4 + wave;
    const int c = chunk & 31;
    const int h = (chunk >> 5) & 15;
    const int b = chunk >> 9;
    const size_t rowbase = ((size_t)(b * T_ + c * L_)) * (3 * D_) + h * DH;
    const int half = lane & 1;

    #pragma unroll
    for (int it = 0; it < 2; ++it) {
        int t = (lane >> 1) + it * 32;
        const unsigned short* kp = qkv + rowbase + (size_t)t * (3 * D_) + D_ + half * 16;
        const unsigned short* vp = qkv + rowbase + (size_t)t * (3 * D_) + 2 * D_ + half * 16;
        bf16x8 k0 = phi_frag(*(const bf16x8*)kp);
        bf16x8 k1 = phi_frag(*(const bf16x8*)(kp + 8));
        bf16x8 v0 = *(const bf16x8*)vp;
        bf16x8 v1 = *(const bf16x8*)(vp + 8);
        #pragma unroll
        for (int i = 0; i < 8; ++i) {
            Kt[wave][half * 16 + i][t]     = (unsigned short)k0[i];
            Kt[wave][half * 16 + 8 + i][t] = (unsigned short)k1[i];
            Vt[wave][half * 16 + i][t]     = (unsigned short)v0[i];
            Vt[wave][half * 16 + 8 + i][t] = (unsigned short)v1[i];
        }
    }
    Vt[wave][32][lane] = 0x3F80;   // ones row
    // same-wave DS ops are in program order; no barrier needed (tiles are per-wave)

    const int fr = lane & 15;
    const int fg = lane >> 4;
    f32x4 acc[3][2];
    #pragma unroll
    for (int m = 0; m < 3; ++m)
        #pragma unroll
        for (int n = 0; n < 2; ++n)
            acc[m][n] = (f32x4){0.f, 0.f, 0.f, 0.f};

    #pragma unroll
    for (int ks = 0; ks < 2; ++ks) {
        int toff = fg * 8 + ks * 32;
        bf16x8 av[3], bk[2];
        #pragma unroll
        for (int m = 0; m < 3; ++m) av[m] = *(const bf16x8*)&Vt[wave][m * 16 + fr][toff];
        #pragma unroll
        for (int n = 0; n < 2; ++n) bk[n] = *(const bf16x8*)&Kt[wave][n * 16 + fr][toff];
        #pragma unroll
        for (int m = 0; m < 3; ++m)
            #pragma unroll
            for (int n = 0; n < 2; ++n)
                acc[m][n] = __builtin_amdgcn_mfma_f32_16x16x32_bf16(av[m], bk[n], acc[m][n], 0, 0, 0);
    }

    float* outp = cSf + (size_t)chunk * (48 * 32);
    #pragma unroll
    for (int m = 0; m < 2; ++m)
        #pragma unroll
        for (int n = 0; n < 2; ++n)
            #pragma unroll
            for (int r = 0; r < 4; ++r)
                outp[(m * 16 + fg * 4 + r) * 32 + n * 16 + fr] = acc[m][n][r];
    if (fg == 0) {   // row 32 = ksum (reg 0 of tile m=2)
        #pragma unroll
        for (int n = 0; n < 2; ++n)
            outp[32 * 32 + n * 16 + fr] = acc[2][n][0];
    }
}

// Exclusive prefix over chunks; emit bf16 transposed state cSt[chunk][e][d].
__global__ __launch_bounds__(256) void chunk_scan(const float* __restrict__ cSf,
                                                  unsigned short* __restrict__ cSt)
{
    int idx = blockIdx.x * 256 + threadIdx.x;     // 32*33*32 = 33792 exactly
    int bh = idx / (33 * 32);
    int r  = idx % (33 * 32);
    float acc = 0.f;
    const float* src = cSf + (size_t)bh * C_ * (48 * 32) + r;
    unsigned short* dst = cSt + (size_t)bh * C_ * (48 * 32) + r;
    #pragma unroll 8
    for (int c = 0; c < C_; ++c) {
        dst[(size_t)c * (48 * 32)] = f2bf(acc);
        acc += src[(size_t)c * (48 * 32)];
    }
}

// Per-chunk output via MFMA. 2 waves per chunk (row halves), 2 chunks per block.
__global__ __launch_bounds__(256) void chunk_out(const unsigned short* __restrict__ qkv,
                                                 const unsigned short* __restrict__ cSt,
                                                 unsigned short* __restrict__ attn)
{
    __shared__ unsigned short Vt[2][48][VTP];
    __shared__ unsigned short Am[4][32][VTP];
    const int tid = threadIdx.x;
    const int lane = tid & 63;
    const int wave = tid >> 6;
    const int ci = wave >> 1;     // chunk within block
    const int wh = wave & 1;      // row half (rows wh*32..wh*32+31)
    const int chunk = blockIdx.x * 2 + ci;
    const int c = chunk & 31;
    const int h = (chunk >> 5) & 15;
    const int b = chunk >> 9;
    const size_t rowbase = ((size_t)(b * T_ + c * L_)) * (3 * D_) + h * DH;
    const int fr = lane & 15;
    const int fg = lane >> 4;

    // build Vt (V transposed + ones row); each wave handles its 32 rows
    {
        int t = wh * 32 + (lane >> 1);
        int half = lane & 1;
        const unsigned short* vp = qkv + rowbase + (size_t)t * (3 * D_) + 2 * D_ + half * 16;
        bf16x8 v0 = *(const bf16x8*)vp;
        bf16x8 v1 = *(const bf16x8*)(vp + 8);
        #pragma unroll
        for (int i = 0; i < 8; ++i) {
            Vt[ci][half * 16 + i][t]     = (unsigned short)v0[i];
            Vt[ci][half * 16 + 8 + i][t] = (unsigned short)v1[i];
        }
        if (half == 0) Vt[ci][32][t] = 0x3F80;
    }

    // Q fragments (phi) direct from global: row tiles m = wh*2 + mm
    bf16x8 aq[2];
    #pragma unroll
    for (int mm = 0; mm < 2; ++mm) {
        int m = wh * 2 + mm;
        const unsigned short* qp = qkv + rowbase + (size_t)(m * 16 + fr) * (3 * D_) + fg * 8;
        aq[mm] = phi_frag(*(const bf16x8*)qp);
    }
    // K fragments (phi): need col tiles n <= wh*2+1
    bf16x8 bk[4];
    const int nmax = wh * 2 + 1;
    #pragma unroll
    for (int n = 0; n < 4; ++n) {
        if (n <= nmax) {
            const unsigned short* kp = qkv + rowbase + (size_t)(n * 16 + fr) * (3 * D_) + D_ + fg * 8;
            bk[n] = phi_frag(*(const bf16x8*)kp);
        }
    }
    // KV-state fragments direct from global cSt (rows e, incl. ks0 at e=32)
    bf16x8 bkv[3];
    #pragma unroll
    for (int n = 0; n < 3; ++n)
        bkv[n] = *(const bf16x8*)&cSt[(size_t)chunk * 1536 + (size_t)(n * 16 + fr) * 32 + fg * 8];

    // acc = Q @ KV0_ext  (col 32 = den contribution q.ks0)
    f32x4 zero = (f32x4){0.f, 0.f, 0.f, 0.f};
    f32x4 acc[2][3];
    #pragma unroll
    for (int mm = 0; mm < 2; ++mm)
        #pragma unroll
        for (int n = 0; n < 3; ++n)
            acc[mm][n] = __builtin_amdgcn_mfma_f32_16x16x32_bf16(aq[mm], bkv[n], zero, 0, 0, 0);

    // S tiles (lower triangle only), masked, to LDS as bf16
    #pragma unroll
    for (int mm = 0; mm < 2; ++mm) {
        int m = wh * 2 + mm;
        #pragma unroll
        for (int n = 0; n < 4; ++n) {
            if (n <= m) {
                f32x4 s = __builtin_amdgcn_mfma_f32_16x16x32_bf16(aq[mm], bk[n], zero, 0, 0, 0);
                #pragma unroll
                for (int r = 0; r < 4; ++r) {
                    unsigned short v = f2bf(s[r]);
                    if (n == m && fr > fg * 4 + r) v = 0;
                    Am[wave][mm * 16 + fg * 4 + r][n * 16 + fr] = v;
                }
            }
        }
    }
    // zero the tile just above the diagonal that the K=32 A@V step will read
    {
        int zc = wh ? 48 : 16;
        *(uint2*)&Am[wave][fr][zc + fg * 4] = (uint2){0u, 0u};
    }
    __syncthreads();

    // acc += A_masked @ V_ext
    #pragma unroll
    for (int ks = 0; ks < 2; ++ks) {
        if (ks <= wh) {
            bf16x8 bv[3];
            #pragma unroll
            for (int n = 0; n < 3; ++n)
                bv[n] = *(const bf16x8*)&Vt[ci][n * 16 + fr][fg * 8 + ks * 32];
            #pragma unroll
            for (int mm = 0; mm < 2; ++mm) {
                bf16x8 aa = *(const bf16x8*)&Am[wave][mm * 16 + fr][fg * 8 + ks * 32];
                #pragma unroll
                for (int n = 0; n < 3; ++n)
                    acc[mm][n] = __builtin_amdgcn_mfma_f32_16x16x32_bf16(aa, bv[n], acc[mm][n], 0, 0, 0);
            }
        }
    }

    // den broadcast (col 32 lives in lanes fr==0), divide, stage out via LDS
    #pragma unroll
    for (int mm = 0; mm < 2; ++mm) {
        float dn[4];
        #pragma unroll
        for (int r = 0; r < 4; ++r)
            dn[r] = __shfl(acc[mm][2][r], lane & 48);
        #pragma unroll
        for (int r = 0; r < 4; ++r) {
            float inv = 1.0f / fmaxf(dn[r], 1e-6f);
            #pragma unroll
            for (int n = 0; n < 2; ++n)
                Am[wave][mm * 16 + fg * 4 + r][n * 16 + fr] = f2bf(acc[mm][n][r] * inv);
        }
    }
    // coalesced store: lane reads one 32B half-row, writes 32B to global
    {
        int lrow = lane >> 1;
        int half = lane & 1;
        uint4 q0 = *(const uint4*)&Am[wave][lrow][half * 16];
        uint4 q1 = *(const uint4*)&Am[wave][lrow][half * 16 + 8];
        size_t grow = (size_t)(b * T_ + c * L_ + wh * 32 + lrow);
        unsigned short* dst = attn + grow * D_ + h * DH + half * 16;
        *(uint4*)dst = q0;
        *(uint4*)(dst + 8) = q1;
    }
}

extern "C" void kernel_launch(void* const* d_in, const int* in_sizes, int n_in,
                              void* d_out, int out_size, void* d_ws, size_t ws_size,
                              hipStream_t stream) {
    const float* x     = (const float*)d_in[0];
    const float* w_qkv = (const float*)d_in[1];
    const float* w_out = (const float*)d_in[2];
    float* out = (float*)d_out;

    char* ws = (char*)d_ws;
    unsigned short* qkvb  = (unsigned short*)ws;                 // 12,582,912 B
    unsigned short* attnb = (unsigned short*)(ws + 12582912);    //  4,194,304 B
    unsigned short* xb    = (unsigned short*)(ws + 16777216);    //  4,194,304 B
    unsigned short* wqb   = (unsigned short*)(ws + 20971520);    //  1,572,864 B
    unsigned short* wob   = (unsigned short*)(ws + 22544384);    //    524,288 B
    float* cSf            = (float*)(ws + 23068672);             //  6,291,456 B  [1024][48][32] f32
    unsigned short* cSt   = (unsigned short*)(ws + 29360128);    //  3,145,728 B  [1024][48][32] bf16
    // total 32,505,856 B

    f32_to_bf16<<<(2097152 / 4 + 255) / 256, 256, 0, stream>>>(x, xb, 2097152 / 4);
    f32_to_bf16<<<(786432 / 4 + 255) / 256, 256, 0, stream>>>(w_qkv, wqb, 786432 / 4);
    f32_to_bf16<<<(262144 / 4 + 255) / 256, 256, 0, stream>>>(w_out, wob, 262144 / 4);

    dim3 g1(4096 / 128, 1536 / 128);
    gemm_bf16_nt<true><<<g1, 256, 0, stream>>>(xb, wqb, qkvb, 4096, 1536, 512);

    chunk_sum<<<NC / 4, 256, 0, stream>>>(qkvb, cSf);
    chunk_scan<<<132, 256, 0, stream>>>(cSf, cSt);
    chunk_out<<<NC / 2, 256, 0, stream>>>(qkvb, cSt, attnb);

    dim3 g2(4096 / 128, 512 / 128);
    gemm_bf16_nt<false><<<g2, 256, 0, stream>>>(attnb, wob, out, 4096, 512, 512);
}

// Round 4
// 55.498 us; speedup vs baseline: 5.0811x; 1.1008x over previous
//
#include <hip/hip_runtime.h>
#include <math.h>

#define B_ 2
#define T_ 2048
#define D_ 512
#define H_ 16
#define DH 32
#define L_ 64
#define C_ 32
#define BH 32
#define NC 1024   // total chunks
#define VTP 72    // LDS row stride (ushorts) for chunk kernels

typedef __attribute__((ext_vector_type(8))) short bf16x8;
typedef __attribute__((ext_vector_type(4))) float f32x4;
typedef __attribute__((ext_vector_type(4))) unsigned short u16x4;

#define AS1 __attribute__((address_space(1)))
#define AS3 __attribute__((address_space(3)))

__device__ __forceinline__ float bf2f(unsigned short u) {
    union { float f; unsigned int i; } v; v.i = ((unsigned int)u) << 16; return v.f;
}
__device__ __forceinline__ unsigned short f2bf(float f) {
    union { float f; unsigned int u; } v; v.f = f;
    unsigned int u = v.u;
    unsigned int r = u + 0x7FFFu + ((u >> 16) & 1u);
    return (unsigned short)(r >> 16);
}
__device__ __forceinline__ bf16x8 phi_frag(bf16x8 in) {
    bf16x8 r;
    #pragma unroll
    for (int i = 0; i < 8; ++i) {
        float f = bf2f((unsigned short)in[i]);
        f = f > 0.f ? f + 1.f : __expf(f);
        r[i] = (short)f2bf(f);
    }
    return r;
}
__device__ __forceinline__ void gload_lds16(const unsigned short* g, unsigned short* l) {
    __builtin_amdgcn_global_load_lds((const AS1 unsigned int*)g, (AS3 unsigned int*)l, 16, 0, 0);
}

// One kernel converts all three fp32 inputs to bf16 (segments in float4 units).
__global__ __launch_bounds__(256) void convert_all(const float* __restrict__ x,
                                                   const float* __restrict__ wq,
                                                   const float* __restrict__ wo,
                                                   unsigned short* __restrict__ xb,
                                                   unsigned short* __restrict__ wqb,
                                                   unsigned short* __restrict__ wob)
{
    int i = blockIdx.x * 256 + threadIdx.x;   // 0 .. 786431
    const float* src; unsigned short* dst; int off;
    if (i < 524288)      { src = x;  dst = xb;  off = i; }
    else if (i < 720896) { src = wq; dst = wqb; off = i - 524288; }
    else                 { src = wo; dst = wob; off = i - 720896; }
    float4 v = ((const float4*)src)[off];
    u16x4 o;
    o.x = f2bf(v.x); o.y = f2bf(v.y); o.z = f2bf(v.z); o.w = f2bf(v.w);
    ((u16x4*)dst)[off] = o;
}

// C[m][n] = sum_k A[m][k]*W[n][k]; 128x128 tile, 4 waves, 16x16x32 bf16 MFMA.
// m97 structure: global_load_lds width-16 staging into LINEAR [128][32] LDS tiles.
template<bool OUT_BF16>
__global__ __launch_bounds__(256) void gemm_bf16_nt(const unsigned short* __restrict__ A,
                                                    const unsigned short* __restrict__ W,
                                                    void* __restrict__ Cout,
                                                    int M, int N, int K)
{
    __shared__ unsigned short As[128][32];
    __shared__ unsigned short Bs[128][32];
    const int tid = threadIdx.x;
    const int lane = tid & 63;
    const int wave = tid >> 6;
    const int wr = wave >> 1;
    const int wc = wave & 1;
    const size_t bm = (size_t)blockIdx.x * 128;
    const size_t bn = (size_t)blockIdx.y * 128;

    // staging: wave stages rows wave*32..wave*32+31 of each tile (2 instrs of 1KB)
    const int srow = wave * 32 + (lane >> 2);
    const int scol = (lane & 3) * 8;
    const unsigned short* ag0 = A + (bm + srow) * (size_t)K + scol;
    const unsigned short* ag1 = ag0 + (size_t)16 * K;
    const unsigned short* bg0 = W + (bn + srow) * (size_t)K + scol;
    const unsigned short* bg1 = bg0 + (size_t)16 * K;
    unsigned short* al0 = &As[wave * 32][0];
    unsigned short* al1 = &As[wave * 32 + 16][0];
    unsigned short* bl0 = &Bs[wave * 32][0];
    unsigned short* bl1 = &Bs[wave * 32 + 16][0];

    f32x4 acc[4][4];
    #pragma unroll
    for (int m = 0; m < 4; ++m)
        #pragma unroll
        for (int n = 0; n < 4; ++n)
            acc[m][n] = (f32x4){0.f, 0.f, 0.f, 0.f};

    const int rr = lane & 15;
    const int kb = (lane >> 4) * 8;

    for (int k0 = 0; k0 < K; k0 += 32) {
        gload_lds16(ag0 + k0, al0);
        gload_lds16(ag1 + k0, al1);
        gload_lds16(bg0 + k0, bl0);
        gload_lds16(bg1 + k0, bl1);
        __syncthreads();
        bf16x8 af[4], bfr[4];
        #pragma unroll
        for (int m = 0; m < 4; ++m) af[m] = *(const bf16x8*)&As[wr * 64 + m * 16 + rr][kb];
        #pragma unroll
        for (int n = 0; n < 4; ++n) bfr[n] = *(const bf16x8*)&Bs[wc * 64 + n * 16 + rr][kb];
        #pragma unroll
        for (int m = 0; m < 4; ++m)
            #pragma unroll
            for (int n = 0; n < 4; ++n)
                acc[m][n] = __builtin_amdgcn_mfma_f32_16x16x32_bf16(af[m], bfr[n], acc[m][n], 0, 0, 0);
        __syncthreads();
    }

    const int cr = (lane >> 4) * 4;
    const int cc = lane & 15;
    #pragma unroll
    for (int m = 0; m < 4; ++m)
        #pragma unroll
        for (int n = 0; n < 4; ++n)
            #pragma unroll
            for (int j = 0; j < 4; ++j) {
                size_t row = bm + wr * 64 + m * 16 + cr + j;
                size_t col = bn + wc * 64 + n * 16 + cc;
                float v = acc[m][n][j];
                if (OUT_BF16) ((unsigned short*)Cout)[row * N + col] = f2bf(v);
                else          ((float*)Cout)[row * N + col] = v;
            }
}

// Per-chunk ST[e][d] = sum_t v_ext[t][e]*phi(k)[t][d], e=0..32 (row 32 = ksum).
__global__ __launch_bounds__(256) void chunk_sum(const unsigned short* __restrict__ qkv,
                                                 float* __restrict__ cSf)
{
    __shared__ unsigned short Kt[4][DH][VTP];
    __shared__ unsigned short Vt[4][48][VTP];
    const int tid = threadIdx.x;
    const int lane = tid & 63;
    const int wave = tid >> 6;
    const int chunk = blockIdx.x * 4 + wave;
    const int c = chunk & 31;
    const int h = (chunk >> 5) & 15;
    const int b = chunk >> 9;
    const size_t rowbase = ((size_t)(b * T_ + c * L_)) * (3 * D_) + h * DH;
    const int half = lane & 1;

    #pragma unroll
    for (int it = 0; it < 2; ++it) {
        int t = (lane >> 1) + it * 32;
        const unsigned short* kp = qkv + rowbase + (size_t)t * (3 * D_) + D_ + half * 16;
        const unsigned short* vp = qkv + rowbase + (size_t)t * (3 * D_) + 2 * D_ + half * 16;
        bf16x8 k0 = phi_frag(*(const bf16x8*)kp);
        bf16x8 k1 = phi_frag(*(const bf16x8*)(kp + 8));
        bf16x8 v0 = *(const bf16x8*)vp;
        bf16x8 v1 = *(const bf16x8*)(vp + 8);
        #pragma unroll
        for (int i = 0; i < 8; ++i) {
            Kt[wave][half * 16 + i][t]     = (unsigned short)k0[i];
            Kt[wave][half * 16 + 8 + i][t] = (unsigned short)k1[i];
            Vt[wave][half * 16 + i][t]     = (unsigned short)v0[i];
            Vt[wave][half * 16 + 8 + i][t] = (unsigned short)v1[i];
        }
    }
    Vt[wave][32][lane] = 0x3F80;   // ones row

    const int fr = lane & 15;
    const int fg = lane >> 4;
    f32x4 acc[3][2];
    #pragma unroll
    for (int m = 0; m < 3; ++m)
        #pragma unroll
        for (int n = 0; n < 2; ++n)
            acc[m][n] = (f32x4){0.f, 0.f, 0.f, 0.f};

    #pragma unroll
    for (int ks = 0; ks < 2; ++ks) {
        int toff = fg * 8 + ks * 32;
        bf16x8 av[3], bk[2];
        #pragma unroll
        for (int m = 0; m < 3; ++m) av[m] = *(const bf16x8*)&Vt[wave][m * 16 + fr][toff];
        #pragma unroll
        for (int n = 0; n < 2; ++n) bk[n] = *(const bf16x8*)&Kt[wave][n * 16 + fr][toff];
        #pragma unroll
        for (int m = 0; m < 3; ++m)
            #pragma unroll
            for (int n = 0; n < 2; ++n)
                acc[m][n] = __builtin_amdgcn_mfma_f32_16x16x32_bf16(av[m], bk[n], acc[m][n], 0, 0, 0);
    }

    float* outp = cSf + (size_t)chunk * (48 * 32);
    #pragma unroll
    for (int m = 0; m < 2; ++m)
        #pragma unroll
        for (int n = 0; n < 2; ++n)
            #pragma unroll
            for (int r = 0; r < 4; ++r)
                outp[(m * 16 + fg * 4 + r) * 32 + n * 16 + fr] = acc[m][n][r];
    if (fg == 0) {
        #pragma unroll
        for (int n = 0; n < 2; ++n)
            outp[32 * 32 + n * 16 + fr] = acc[2][n][0];
    }
}

// Exclusive prefix over chunks; emit bf16 transposed state cSt[chunk][e][d].
__global__ __launch_bounds__(256) void chunk_scan(const float* __restrict__ cSf,
                                                  unsigned short* __restrict__ cSt)
{
    int idx = blockIdx.x * 256 + threadIdx.x;     // 32*33*32 = 33792 exactly
    int bh = idx / (33 * 32);
    int r  = idx % (33 * 32);
    float acc = 0.f;
    const float* src = cSf + (size_t)bh * C_ * (48 * 32) + r;
    unsigned short* dst = cSt + (size_t)bh * C_ * (48 * 32) + r;
    #pragma unroll 8
    for (int c = 0; c < C_; ++c) {
        dst[(size_t)c * (48 * 32)] = f2bf(acc);
        acc += src[(size_t)c * (48 * 32)];
    }
}

// Per-chunk output via MFMA. 2 waves per chunk (row halves), 2 chunks per block.
__global__ __launch_bounds__(256) void chunk_out(const unsigned short* __restrict__ qkv,
                                                 const unsigned short* __restrict__ cSt,
                                                 unsigned short* __restrict__ attn)
{
    __shared__ unsigned short Vt[2][48][VTP];
    __shared__ unsigned short Am[4][32][VTP];
    const int tid = threadIdx.x;
    const int lane = tid & 63;
    const int wave = tid >> 6;
    const int ci = wave >> 1;
    const int wh = wave & 1;
    const int chunk = blockIdx.x * 2 + ci;
    const int c = chunk & 31;
    const int h = (chunk >> 5) & 15;
    const int b = chunk >> 9;
    const size_t rowbase = ((size_t)(b * T_ + c * L_)) * (3 * D_) + h * DH;
    const int fr = lane & 15;
    const int fg = lane >> 4;

    {
        int t = wh * 32 + (lane >> 1);
        int half = lane & 1;
        const unsigned short* vp = qkv + rowbase + (size_t)t * (3 * D_) + 2 * D_ + half * 16;
        bf16x8 v0 = *(const bf16x8*)vp;
        bf16x8 v1 = *(const bf16x8*)(vp + 8);
        #pragma unroll
        for (int i = 0; i < 8; ++i) {
            Vt[ci][half * 16 + i][t]     = (unsigned short)v0[i];
            Vt[ci][half * 16 + 8 + i][t] = (unsigned short)v1[i];
        }
        if (half == 0) Vt[ci][32][t] = 0x3F80;
    }

    bf16x8 aq[2];
    #pragma unroll
    for (int mm = 0; mm < 2; ++mm) {
        int m = wh * 2 + mm;
        const unsigned short* qp = qkv + rowbase + (size_t)(m * 16 + fr) * (3 * D_) + fg * 8;
        aq[mm] = phi_frag(*(const bf16x8*)qp);
    }
    bf16x8 bk[4];
    const int nmax = wh * 2 + 1;
    #pragma unroll
    for (int n = 0; n < 4; ++n) {
        if (n <= nmax) {
            const unsigned short* kp = qkv + rowbase + (size_t)(n * 16 + fr) * (3 * D_) + D_ + fg * 8;
            bk[n] = phi_frag(*(const bf16x8*)kp);
        }
    }
    bf16x8 bkv[3];
    #pragma unroll
    for (int n = 0; n < 3; ++n)
        bkv[n] = *(const bf16x8*)&cSt[(size_t)chunk * 1536 + (size_t)(n * 16 + fr) * 32 + fg * 8];

    f32x4 zero = (f32x4){0.f, 0.f, 0.f, 0.f};
    f32x4 acc[2][3];
    #pragma unroll
    for (int mm = 0; mm < 2; ++mm)
        #pragma unroll
        for (int n = 0; n < 3; ++n)
            acc[mm][n] = __builtin_amdgcn_mfma_f32_16x16x32_bf16(aq[mm], bkv[n], zero, 0, 0, 0);

    #pragma unroll
    for (int mm = 0; mm < 2; ++mm) {
        int m = wh * 2 + mm;
        #pragma unroll
        for (int n = 0; n < 4; ++n) {
            if (n <= m) {
                f32x4 s = __builtin_amdgcn_mfma_f32_16x16x32_bf16(aq[mm], bk[n], zero, 0, 0, 0);
                #pragma unroll
                for (int r = 0; r < 4; ++r) {
                    unsigned short v = f2bf(s[r]);
                    if (n == m && fr > fg * 4 + r) v = 0;
                    Am[wave][mm * 16 + fg * 4 + r][n * 16 + fr] = v;
                }
            }
        }
    }
    {
        int zc = wh ? 48 : 16;
        *(uint2*)&Am[wave][fr][zc + fg * 4] = (uint2){0u, 0u};
    }
    __syncthreads();

    #pragma unroll
    for (int ks = 0; ks < 2; ++ks) {
        if (ks <= wh) {
            bf16x8 bv[3];
            #pragma unroll
            for (int n = 0; n < 3; ++n)
                bv[n] = *(const bf16x8*)&Vt[ci][n * 16 + fr][fg * 8 + ks * 32];
            #pragma unroll
            for (int mm = 0; mm < 2; ++mm) {
                bf16x8 aa = *(const bf16x8*)&Am[wave][mm * 16 + fr][fg * 8 + ks * 32];
                #pragma unroll
                for (int n = 0; n < 3; ++n)
                    acc[mm][n] = __builtin_amdgcn_mfma_f32_16x16x32_bf16(aa, bv[n], acc[mm][n], 0, 0, 0);
            }
        }
    }

    #pragma unroll
    for (int mm = 0; mm < 2; ++mm) {
        float dn[4];
        #pragma unroll
        for (int r = 0; r < 4; ++r)
            dn[r] = __shfl(acc[mm][2][r], lane & 48);
        #pragma unroll
        for (int r = 0; r < 4; ++r) {
            float inv = 1.0f / fmaxf(dn[r], 1e-6f);
            #pragma unroll
            for (int n = 0; n < 2; ++n)
                Am[wave][mm * 16 + fg * 4 + r][n * 16 + fr] = f2bf(acc[mm][n][r] * inv);
        }
    }
    {
        int lrow = lane >> 1;
        int half = lane & 1;
        uint4 q0 = *(const uint4*)&Am[wave][lrow][half * 16];
        uint4 q1 = *(const uint4*)&Am[wave][lrow][half * 16 + 8];
        size_t grow = (size_t)(b * T_ + c * L_ + wh * 32 + lrow);
        unsigned short* dst = attn + grow * D_ + h * DH + half * 16;
        *(uint4*)dst = q0;
        *(uint4*)(dst + 8) = q1;
    }
}

extern "C" void kernel_launch(void* const* d_in, const int* in_sizes, int n_in,
                              void* d_out, int out_size, void* d_ws, size_t ws_size,
                              hipStream_t stream) {
    const float* x     = (const float*)d_in[0];
    const float* w_qkv = (const float*)d_in[1];
    const float* w_out = (const float*)d_in[2];
    float* out = (float*)d_out;

    char* ws = (char*)d_ws;
    unsigned short* qkvb  = (unsigned short*)ws;                 // 12,582,912 B
    unsigned short* attnb = (unsigned short*)(ws + 12582912);    //  4,194,304 B
    unsigned short* xb    = (unsigned short*)(ws + 16777216);    //  4,194,304 B
    unsigned short* wqb   = (unsigned short*)(ws + 20971520);    //  1,572,864 B
    unsigned short* wob   = (unsigned short*)(ws + 22544384);    //    524,288 B
    float* cSf            = (float*)(ws + 23068672);             //  6,291,456 B
    unsigned short* cSt   = (unsigned short*)(ws + 29360128);    //  3,145,728 B
    // total 32,505,856 B

    convert_all<<<3072, 256, 0, stream>>>(x, w_qkv, w_out, xb, wqb, wob);

    dim3 g1(4096 / 128, 1536 / 128);
    gemm_bf16_nt<true><<<g1, 256, 0, stream>>>(xb, wqb, qkvb, 4096, 1536, 512);

    chunk_sum<<<NC / 4, 256, 0, stream>>>(qkvb, cSf);
    chunk_scan<<<132, 256, 0, stream>>>(cSf, cSt);
    chunk_out<<<NC / 2, 256, 0, stream>>>(qkvb, cSt, attnb);

    dim3 g2(4096 / 128, 512 / 128);
    gemm_bf16_nt<false><<<g2, 256, 0, stream>>>(attnb, wob, out, 4096, 512, 512);
}